// Round 16
// baseline (103.021 us; speedup 1.0000x reference)
//
#include <hip/hip_runtime.h>
#include <hip/hip_bf16.h>

#define CIN  128
#define FOUT 128
#define HID  32
#define BIG_SH 7
#define BIGW  128           // 1 << BIG_SH
#define CAPBIN 2560         // coarse-bin capacity (mean 2048, +11 sigma)
#define SUBW  32            // agg sub-range width
#define NSUB  4             // BIGW / SUBW
#define CAPV  40            // per-vertex capacity (mean 16, Poisson +8 sigma)
#define EPSV 1e-8f

typedef __attribute__((ext_vector_type(8))) short bf16x8;
typedef __attribute__((ext_vector_type(4))) float f32x4;

__device__ inline short f2bf(float x) {
    union { float f; unsigned u; } v; v.f = x;
    unsigned r = v.u + 0x7fffu + ((v.u >> 16) & 1u);
    return (short)(r >> 16);
}
__device__ inline float bfbits2f(unsigned b) {
    union { unsigned u; float f; } v; v.u = b << 16;
    return v.f;
}

// ---------------------------------------------------------------------------
// Merged prep + binning. Head: elementwise prep (WcT/W1T transposes, padded
// verts) — independent of the edge pass, no barrier needed. Body: two-level
// binning with block-owned run reservation (proven r13/r15). binctr is
// zeroed by hipMemsetAsync before this kernel.
// Grid: 196 blocks covers both E/4096 edge slices and N/256 prep slices.
// ---------------------------------------------------------------------------
__global__ __launch_bounds__(256) void binprep_kernel(
    const int* __restrict__ edges,
    const float* __restrict__ Wc,
    const float* __restrict__ W1,
    const float* __restrict__ verts,
    int* __restrict__ binctr,
    unsigned* __restrict__ binbuf,
    short* __restrict__ WcT,
    short* __restrict__ W1T,
    float* __restrict__ vertsP,
    int N, int E, int nbins) {
    __shared__ int cnt[512];
    __shared__ int base[512];
    const int tid = threadIdx.x;
    const int gidx = blockIdx.x * 256 + tid;

    // ---- prep head (independent elementwise work) ----
    if (gidx < CIN * FOUT) {
        const int c = gidx >> 7, k = gidx & 127;
        WcT[c * CIN + k] = f2bf(Wc[k * FOUT + c]);
    }
    if (gidx < HID * CIN) {
        const int c = gidx >> 7, k = gidx & 127;
        W1T[c * CIN + k] = f2bf(W1[k * HID + c]);
    }
    if (gidx < N) {
        vertsP[gidx * 4 + 0] = verts[gidx * 3 + 0];
        vertsP[gidx * 4 + 1] = verts[gidx * 3 + 1];
        vertsP[gidx * 4 + 2] = verts[gidx * 3 + 2];
        vertsP[gidx * 4 + 3] = 0.f;
    }

    // ---- binning body ----
    for (int b = tid; b < nbins; b += 256) cnt[b] = 0;
    __syncthreads();

    int ebin[16], erank[16]; unsigned epack[16];
    const int e0 = blockIdx.x * 4096;
#pragma unroll
    for (int i = 0; i < 16; ++i) {
        const int e = e0 + i * 256 + tid;
        ebin[i] = -1;
        if (e < E) {
            const int s = edges[e];
            const int d = edges[E + e];
            ebin[i] = s >> BIG_SH;
            epack[i] = ((unsigned)(s & (BIGW - 1)) << 16) | (unsigned)d;
            erank[i] = atomicAdd(&cnt[ebin[i]], 1);
        }
    }
    __syncthreads();
    for (int b = tid; b < nbins; b += 256) {
        const int c = cnt[b];
        base[b] = c ? atomicAdd(&binctr[b], c) : 0;
    }
    __syncthreads();
#pragma unroll
    for (int i = 0; i < 16; ++i) {
        if (ebin[i] >= 0) {
            const int rk = base[ebin[i]] + erank[i];
            if (rk < CAPBIN) binbuf[(size_t)ebin[i] * CAPBIN + rk] = epack[i];
        }
    }
}

// ---------------------------------------------------------------------------
// Per-16-vertex wave: MFMA xw = feat@Wc (bf16), h = relu(feat@W1+b1),
// M = h@W2+b2, packed symmetric G = M^T M (6 vals, stride 8).
// ---------------------------------------------------------------------------
__global__ __launch_bounds__(256) void vertex_mfma(
    const float* __restrict__ feat,
    const short* __restrict__ WcT,    // [FOUT][CIN] bf16
    const short* __restrict__ W1T,    // [HID][CIN] bf16
    const float* __restrict__ b1,
    const float* __restrict__ W2,     // [HID][9]
    const float* __restrict__ b2,
    float* __restrict__ Gp,           // [N][8] packed symmetric
    unsigned short* __restrict__ xwb, // [N][FOUT] bf16 bits
    int N) {
    __shared__ unsigned short xw_s[4][16][FOUT];
    __shared__ float h_lds[4][16][HID];
    __shared__ float M_lds[4][16][9];
    const int wid  = threadIdx.x >> 6;
    const int lane = threadIdx.x & 63;
    const int v0   = (blockIdx.x * 4 + wid) * 16;
    const int r    = lane & 15;
    const int hi   = lane >> 4;
    const int vr   = min(v0 + r, N - 1);

    bf16x8 a[4];
#pragma unroll
    for (int kt = 0; kt < 4; ++kt) {
        const float* src = feat + (size_t)vr * CIN + kt * 32 + hi * 8;
        const float4 f0 = ((const float4*)src)[0];
        const float4 f1 = ((const float4*)src)[1];
        bf16x8 t;
        t[0] = f2bf(f0.x); t[1] = f2bf(f0.y); t[2] = f2bf(f0.z); t[3] = f2bf(f0.w);
        t[4] = f2bf(f1.x); t[5] = f2bf(f1.y); t[6] = f2bf(f1.z); t[7] = f2bf(f1.w);
        a[kt] = t;
    }

#pragma unroll
    for (int ct = 0; ct < 8; ++ct) {
        f32x4 acc = {0.f, 0.f, 0.f, 0.f};
#pragma unroll
        for (int kt = 0; kt < 4; ++kt) {
            const bf16x8 b = *((const bf16x8*)(WcT + (size_t)(ct * 16 + r) * CIN + kt * 32 + hi * 8));
            acc = __builtin_amdgcn_mfma_f32_16x16x32_bf16(a[kt], b, acc, 0, 0, 0);
        }
#pragma unroll
        for (int reg = 0; reg < 4; ++reg)
            xw_s[wid][hi * 4 + reg][ct * 16 + r] = (unsigned short)f2bf(acc[reg]);
    }

#pragma unroll
    for (int row = 0; row < 16; ++row) {
        if (v0 + row < N) {
            const unsigned d = ((const unsigned*)xw_s[wid][row])[lane];
            ((unsigned*)(xwb + (size_t)(v0 + row) * FOUT))[lane] = d;
        }
    }

#pragma unroll
    for (int ct = 0; ct < 2; ++ct) {
        f32x4 acc = {0.f, 0.f, 0.f, 0.f};
#pragma unroll
        for (int kt = 0; kt < 4; ++kt) {
            const bf16x8 b = *((const bf16x8*)(W1T + (size_t)(ct * 16 + r) * CIN + kt * 32 + hi * 8));
            acc = __builtin_amdgcn_mfma_f32_16x16x32_bf16(a[kt], b, acc, 0, 0, 0);
        }
        const float bb = b1[ct * 16 + r];
#pragma unroll
        for (int reg = 0; reg < 4; ++reg)
            h_lds[wid][hi * 4 + reg][ct * 16 + r] = fmaxf(acc[reg] + bb, 0.f);
    }
    __syncthreads();

    for (int idx = lane; idx < 144; idx += 64) {
        const int v = idx / 9, t = idx - v * 9;
        float m = b2[t];
#pragma unroll
        for (int k = 0; k < HID; ++k)
            m = fmaf(h_lds[wid][v][k], W2[k * 9 + t], m);
        M_lds[wid][v][t] = m;
    }
    __syncthreads();

    for (int idx = lane; idx < 96; idx += 64) {
        const int v = idx / 6, t = idx - v * 6;
        const int i = (t >= 3) + (t >= 5);
        const int j = t - (t >= 3) * 2 - (t >= 5);
        float g = 0.f;
#pragma unroll
        for (int k = 0; k < 3; ++k)
            g += M_lds[wid][v][k * 3 + i] * M_lds[wid][v][k * 3 + j];
        if (v0 + v < N) Gp[(size_t)(v0 + v) * 8 + t] = g;
    }
}

// ---------------------------------------------------------------------------
// Aggregation v5: 4 sub-blocks per coarse bin (1564 blocks). Single uint4
// scan of binbuf (4x fewer scan loads): filter own sub-range, compute w
// (s-side LDS preload), direct LDS bucket by vertex. Then 4 waves x 8
// vertices do 8-wide unrolled wave-wide xwb row gathers.
// ---------------------------------------------------------------------------
__global__ __launch_bounds__(256) void agg_kernel(const int* __restrict__ binctr,
                                                  const unsigned* __restrict__ binbuf,
                                                  const float* __restrict__ vertsP,
                                                  const float* __restrict__ Gp,
                                                  const unsigned short* __restrict__ xwb,
                                                  const float* __restrict__ bias,
                                                  float* __restrict__ out,
                                                  int N) {
    __shared__ unsigned short dloc[SUBW][CAPV];
    __shared__ float wloc[SUBW][CAPV];
    __shared__ int cnt[SUBW];
    __shared__ float sG[SUBW * 8];
    __shared__ float sV[SUBW * 4];

    const int b   = blockIdx.x >> 2;
    const int sub = blockIdx.x & 3;
    const int v0  = (b << BIG_SH) + sub * SUBW;
    const int tid = threadIdx.x;

    if (tid < SUBW) cnt[tid] = 0;
    {
        const int v = v0 + (tid >> 3);
        sG[tid] = (v < N) ? Gp[(size_t)v * 8 + (tid & 7)] : 0.f;
    }
    if (tid < SUBW * 4) {
        const int v2 = v0 + (tid >> 2);
        sV[tid] = (v2 < N) ? vertsP[(size_t)v2 * 4 + (tid & 3)] : 0.f;
    }
    __syncthreads();

    const int n = min(binctr[b], CAPBIN);

    // single scan via uint4, filter + weight + direct bucket
    auto process = [&](unsigned p) {
        const int ls = (int)(p >> 16);
        if ((ls >> 5) != sub) return;
        const int l = ls & 31;
        const int d = (int)(p & 0xffffu);

        const float4 vd = ((const float4*)vertsP)[d];
        const float4 ha = ((const float4*)(Gp + (size_t)d * 8))[0];
        const float2 hb = ((const float2*)(Gp + (size_t)d * 8 + 4))[0];
        const float* gs = &sG[l * 8];
        const float* vv = &sV[l * 4];
        const float t0 = vd.x - vv[0], t1 = vd.y - vv[1], t2 = vd.z - vv[2];
        const float g00 = gs[0] + ha.x, g01 = gs[1] + ha.y, g02 = gs[2] + ha.z;
        const float g11 = gs[3] + ha.w, g12 = gs[4] + hb.x, g22 = gs[5] + hb.y;
        const float q = 0.5f * (g00 * t0 * t0 + g11 * t1 * t1 + g22 * t2 * t2
                      + 2.f * (g01 * t0 * t1 + g02 * t0 * t2 + g12 * t1 * t2));
        const float w = __expf(-q);

        const int rk = atomicAdd(&cnt[l], 1);
        if (rk < CAPV) { dloc[l][rk] = (unsigned short)d; wloc[l][rk] = w; }
    };

    const uint4* bb4 = (const uint4*)(binbuf + (size_t)b * CAPBIN);
    const int n4 = n >> 2;
    for (int i = tid; i < n4; i += 256) {
        const uint4 p4 = bb4[i];
        process(p4.x); process(p4.y); process(p4.z); process(p4.w);
    }
    for (int i = (n4 << 2) + tid; i < n; i += 256)
        process(binbuf[(size_t)b * CAPBIN + i]);
    __syncthreads();

    // 4 waves x 8 vertices
    const int wid  = tid >> 6;
    const int lane = tid & 63;
    const float2 bb = ((const float2*)bias)[lane];

    for (int l = wid * 8; l < wid * 8 + 8; ++l) {
        const int v = v0 + l;
        if (v >= N) break;
        const int deg = min(cnt[l], CAPV);

        float ax = 0.f, ay = 0.f, wsum = 0.f;
        int k = 0;
        for (; k + 8 <= deg; k += 8) {
            int   d_[8]; float w_[8]; unsigned u_[8];
#pragma unroll
            for (int j = 0; j < 8; ++j) { d_[j] = dloc[l][k + j]; w_[j] = wloc[l][k + j]; }
#pragma unroll
            for (int j = 0; j < 8; ++j) u_[j] = ((const unsigned*)(xwb + (size_t)d_[j] * FOUT))[lane];
#pragma unroll
            for (int j = 0; j < 8; ++j) {
                ax = fmaf(w_[j], bfbits2f(u_[j] & 0xffffu), ax);
                ay = fmaf(w_[j], bfbits2f(u_[j] >> 16), ay);
                wsum += w_[j];
            }
        }
        for (; k < deg; ++k) {
            const int   d0 = dloc[l][k];
            const float w0 = wloc[l][k];
            const unsigned u0 = ((const unsigned*)(xwb + (size_t)d0 * FOUT))[lane];
            ax = fmaf(w0, bfbits2f(u0 & 0xffffu), ax);
            ay = fmaf(w0, bfbits2f(u0 >> 16), ay);
            wsum += w0;
        }

        const float inv = 1.f / (wsum + EPSV);
        float2 o;
        o.x = ax * inv + bb.x;
        o.y = ay * inv + bb.y;
        ((float2*)(out + (size_t)v * FOUT))[lane] = o;
    }
}

extern "C" void kernel_launch(void* const* d_in, const int* in_sizes, int n_in,
                              void* d_out, int out_size, void* d_ws, size_t ws_size,
                              hipStream_t stream) {
    const float* feat  = (const float*)d_in[0];
    const float* verts = (const float*)d_in[1];
    const int*   edges = (const int*)d_in[2];
    // d_in[3] = faces (unused)
    const float* W1    = (const float*)d_in[4];
    const float* b1    = (const float*)d_in[5];
    const float* W2    = (const float*)d_in[6];
    const float* b2    = (const float*)d_in[7];
    const float* Wc    = (const float*)d_in[8];
    const float* bias  = (const float*)d_in[9];

    const int N = in_sizes[0] / CIN;
    const int E = in_sizes[2] / 2;
    const int nbins = (N + BIGW - 1) >> BIG_SH;

    // workspace layout (256B-aligned chunks)
    char* p = (char*)d_ws;
    auto alloc = [&](size_t bytes) {
        char* r = p;
        p += (bytes + 255) & ~(size_t)255;
        return r;
    };
    short*          WcT    = (short*)alloc((size_t)CIN * FOUT * sizeof(short));
    short*          W1T    = (short*)alloc((size_t)HID * CIN * sizeof(short));
    unsigned short* xwb    = (unsigned short*)alloc((size_t)N * FOUT * sizeof(short));
    float*          Gp     = (float*)alloc((size_t)N * 8 * sizeof(float));
    float*          vertsP = (float*)alloc((size_t)N * 4 * sizeof(float));
    unsigned*       binbuf = (unsigned*)alloc((size_t)nbins * CAPBIN * sizeof(unsigned));
    int*            binctr = (int*)alloc((size_t)nbins * sizeof(int));
    float*          out    = (float*)d_out;

    hipMemsetAsync(binctr, 0, (size_t)nbins * sizeof(int), stream);

    const int nbp = ((E + 4095) / 4096 > (N + 255) / 256) ? (E + 4095) / 4096 : (N + 255) / 256;
    binprep_kernel<<<nbp, 256, 0, stream>>>(edges, Wc, W1, verts, binctr, binbuf,
                                            WcT, W1T, vertsP, N, E, nbins);

    const int nwaves = (N + 15) / 16;
    vertex_mfma<<<(nwaves + 3) / 4, 256, 0, stream>>>(feat, WcT, W1T, b1, W2, b2, Gp, xwb, N);

    agg_kernel<<<nbins * NSUB, 256, 0, stream>>>(binctr, binbuf, vertsP, Gp, xwb, bias, out, N);
}

// Round 17
// 100.798 us; speedup vs baseline: 1.0221x; 1.0221x over previous
//
#include <hip/hip_runtime.h>
#include <hip/hip_bf16.h>

#define CIN  128
#define FOUT 128
#define HID  32
#define BIG_SH 7
#define BIGW  128           // 1 << BIG_SH
#define CAPBIN 2560         // coarse-bin capacity (mean 2048, +11 sigma)
#define SUBW  32            // agg sub-range width
#define NSUB  4             // BIGW / SUBW
#define CAPV  40            // per-vertex capacity (mean 16, Poisson +8 sigma)
#define EPSV 1e-8f

typedef __attribute__((ext_vector_type(8))) short bf16x8;
typedef __attribute__((ext_vector_type(4))) float f32x4;

__device__ inline short f2bf(float x) {
    union { float f; unsigned u; } v; v.f = x;
    unsigned r = v.u + 0x7fffu + ((v.u >> 16) & 1u);
    return (short)(r >> 16);
}
__device__ inline float bfbits2f(unsigned b) {
    union { unsigned u; float f; } v; v.u = b << 16;
    return v.f;
}

// ---------------------------------------------------------------------------
// Prep: WcT/W1T bf16 transposes, padded verts [N][4], zero bin counters.
// ---------------------------------------------------------------------------
__global__ void prep_kernel(const float* __restrict__ Wc,
                            const float* __restrict__ W1,
                            const float* __restrict__ verts,
                            short* __restrict__ WcT,
                            short* __restrict__ W1T,
                            float* __restrict__ vertsP,
                            int* __restrict__ binctr,
                            int N, int nbins) {
    const int idx = blockIdx.x * 256 + threadIdx.x;
    if (idx < CIN * FOUT) {
        const int c = idx >> 7, k = idx & 127;
        WcT[c * CIN + k] = f2bf(Wc[k * FOUT + c]);
    }
    if (idx < HID * CIN) {
        const int c = idx >> 7, k = idx & 127;
        W1T[c * CIN + k] = f2bf(W1[k * HID + c]);
    }
    if (idx < N) {
        vertsP[idx * 4 + 0] = verts[idx * 3 + 0];
        vertsP[idx * 4 + 1] = verts[idx * 3 + 1];
        vertsP[idx * 4 + 2] = verts[idx * 3 + 2];
        vertsP[idx * 4 + 3] = 0.f;
    }
    if (idx < nbins) binctr[idx] = 0;
}

// ---------------------------------------------------------------------------
// Two-level binning with block-owned run reservation (proven r13/r15), one
// LDS-atomic pass: counting atomicAdd's return value is the in-block rank.
// ---------------------------------------------------------------------------
__global__ __launch_bounds__(256) void bin_kernel(const int* __restrict__ edges,
                                                  int* __restrict__ binctr,
                                                  unsigned* __restrict__ binbuf,
                                                  int E, int nbins) {
    __shared__ int cnt[512];
    __shared__ int base[512];
    const int tid = threadIdx.x;
    for (int b = tid; b < nbins; b += 256) cnt[b] = 0;
    __syncthreads();

    int ebin[16], erank[16]; unsigned epack[16];
    const int e0 = blockIdx.x * 4096;
#pragma unroll
    for (int i = 0; i < 16; ++i) {
        const int e = e0 + i * 256 + tid;
        ebin[i] = -1;
        if (e < E) {
            const int s = edges[e];
            const int d = edges[E + e];
            ebin[i] = s >> BIG_SH;
            epack[i] = ((unsigned)(s & (BIGW - 1)) << 16) | (unsigned)d;
            erank[i] = atomicAdd(&cnt[ebin[i]], 1);
        }
    }
    __syncthreads();
    for (int b = tid; b < nbins; b += 256) {
        const int c = cnt[b];
        base[b] = c ? atomicAdd(&binctr[b], c) : 0;
    }
    __syncthreads();
#pragma unroll
    for (int i = 0; i < 16; ++i) {
        if (ebin[i] >= 0) {
            const int rk = base[ebin[i]] + erank[i];
            if (rk < CAPBIN) binbuf[(size_t)ebin[i] * CAPBIN + rk] = epack[i];
        }
    }
}

// ---------------------------------------------------------------------------
// Per-16-vertex wave: MFMA xw = feat@Wc (bf16), h = relu(feat@W1+b1),
// M = h@W2+b2, packed symmetric G = M^T M (6 vals, stride 8).
// ---------------------------------------------------------------------------
__global__ __launch_bounds__(256) void vertex_mfma(
    const float* __restrict__ feat,
    const short* __restrict__ WcT,    // [FOUT][CIN] bf16
    const short* __restrict__ W1T,    // [HID][CIN] bf16
    const float* __restrict__ b1,
    const float* __restrict__ W2,     // [HID][9]
    const float* __restrict__ b2,
    float* __restrict__ Gp,           // [N][8] packed symmetric
    unsigned short* __restrict__ xwb, // [N][FOUT] bf16 bits
    int N) {
    __shared__ unsigned short xw_s[4][16][FOUT];
    __shared__ float h_lds[4][16][HID];
    __shared__ float M_lds[4][16][9];
    const int wid  = threadIdx.x >> 6;
    const int lane = threadIdx.x & 63;
    const int v0   = (blockIdx.x * 4 + wid) * 16;
    const int r    = lane & 15;
    const int hi   = lane >> 4;
    const int vr   = min(v0 + r, N - 1);

    bf16x8 a[4];
#pragma unroll
    for (int kt = 0; kt < 4; ++kt) {
        const float* src = feat + (size_t)vr * CIN + kt * 32 + hi * 8;
        const float4 f0 = ((const float4*)src)[0];
        const float4 f1 = ((const float4*)src)[1];
        bf16x8 t;
        t[0] = f2bf(f0.x); t[1] = f2bf(f0.y); t[2] = f2bf(f0.z); t[3] = f2bf(f0.w);
        t[4] = f2bf(f1.x); t[5] = f2bf(f1.y); t[6] = f2bf(f1.z); t[7] = f2bf(f1.w);
        a[kt] = t;
    }

#pragma unroll
    for (int ct = 0; ct < 8; ++ct) {
        f32x4 acc = {0.f, 0.f, 0.f, 0.f};
#pragma unroll
        for (int kt = 0; kt < 4; ++kt) {
            const bf16x8 b = *((const bf16x8*)(WcT + (size_t)(ct * 16 + r) * CIN + kt * 32 + hi * 8));
            acc = __builtin_amdgcn_mfma_f32_16x16x32_bf16(a[kt], b, acc, 0, 0, 0);
        }
#pragma unroll
        for (int reg = 0; reg < 4; ++reg)
            xw_s[wid][hi * 4 + reg][ct * 16 + r] = (unsigned short)f2bf(acc[reg]);
    }

#pragma unroll
    for (int row = 0; row < 16; ++row) {
        if (v0 + row < N) {
            const unsigned d = ((const unsigned*)xw_s[wid][row])[lane];
            ((unsigned*)(xwb + (size_t)(v0 + row) * FOUT))[lane] = d;
        }
    }

#pragma unroll
    for (int ct = 0; ct < 2; ++ct) {
        f32x4 acc = {0.f, 0.f, 0.f, 0.f};
#pragma unroll
        for (int kt = 0; kt < 4; ++kt) {
            const bf16x8 b = *((const bf16x8*)(W1T + (size_t)(ct * 16 + r) * CIN + kt * 32 + hi * 8));
            acc = __builtin_amdgcn_mfma_f32_16x16x32_bf16(a[kt], b, acc, 0, 0, 0);
        }
        const float bb = b1[ct * 16 + r];
#pragma unroll
        for (int reg = 0; reg < 4; ++reg)
            h_lds[wid][hi * 4 + reg][ct * 16 + r] = fmaxf(acc[reg] + bb, 0.f);
    }
    __syncthreads();

    for (int idx = lane; idx < 144; idx += 64) {
        const int v = idx / 9, t = idx - v * 9;
        float m = b2[t];
#pragma unroll
        for (int k = 0; k < HID; ++k)
            m = fmaf(h_lds[wid][v][k], W2[k * 9 + t], m);
        M_lds[wid][v][t] = m;
    }
    __syncthreads();

    for (int idx = lane; idx < 96; idx += 64) {
        const int v = idx / 6, t = idx - v * 6;
        const int i = (t >= 3) + (t >= 5);
        const int j = t - (t >= 3) * 2 - (t >= 5);
        float g = 0.f;
#pragma unroll
        for (int k = 0; k < 3; ++k)
            g += M_lds[wid][v][k * 3 + i] * M_lds[wid][v][k * 3 + j];
        if (v0 + v < N) Gp[(size_t)(v0 + v) * 8 + t] = g;
    }
}

// ---------------------------------------------------------------------------
// Aggregation v6: 4 sub-blocks per coarse bin. Phase 1: uint4 scan, filter,
// weight, direct LDS bucket (as r15/r16). Phase 2 NEW: lane = (group g =
// lane>>4, chunk j = lane&15); each group gathers a DIFFERENT dst row via
// uint4 (16 B/lane) -> 4 rows in flight per wave-wide load, 4x fewer VMEM
// instructions. Two shfl_xor rounds fold group partials; group 0 stores.
// ---------------------------------------------------------------------------
__global__ __launch_bounds__(256) void agg_kernel(const int* __restrict__ binctr,
                                                  const unsigned* __restrict__ binbuf,
                                                  const float* __restrict__ vertsP,
                                                  const float* __restrict__ Gp,
                                                  const unsigned short* __restrict__ xwb,
                                                  const float* __restrict__ bias,
                                                  float* __restrict__ out,
                                                  int N) {
    __shared__ unsigned short dloc[SUBW][CAPV];
    __shared__ float wloc[SUBW][CAPV];
    __shared__ int cnt[SUBW];
    __shared__ float sG[SUBW * 8];
    __shared__ float sV[SUBW * 4];

    const int b   = blockIdx.x >> 2;
    const int sub = blockIdx.x & 3;
    const int v0  = (b << BIG_SH) + sub * SUBW;
    const int tid = threadIdx.x;

    if (tid < SUBW) cnt[tid] = 0;
    {
        const int v = v0 + (tid >> 3);
        sG[tid] = (v < N) ? Gp[(size_t)v * 8 + (tid & 7)] : 0.f;
    }
    if (tid < SUBW * 4) {
        const int v2 = v0 + (tid >> 2);
        sV[tid] = (v2 < N) ? vertsP[(size_t)v2 * 4 + (tid & 3)] : 0.f;
    }
    __syncthreads();

    const int n = min(binctr[b], CAPBIN);

    auto process = [&](unsigned p) {
        const int ls = (int)(p >> 16);
        if ((ls >> 5) != sub) return;
        const int l = ls & 31;
        const int d = (int)(p & 0xffffu);

        const float4 vd = ((const float4*)vertsP)[d];
        const float4 ha = ((const float4*)(Gp + (size_t)d * 8))[0];
        const float2 hb = ((const float2*)(Gp + (size_t)d * 8 + 4))[0];
        const float* gs = &sG[l * 8];
        const float* vv = &sV[l * 4];
        const float t0 = vd.x - vv[0], t1 = vd.y - vv[1], t2 = vd.z - vv[2];
        const float g00 = gs[0] + ha.x, g01 = gs[1] + ha.y, g02 = gs[2] + ha.z;
        const float g11 = gs[3] + ha.w, g12 = gs[4] + hb.x, g22 = gs[5] + hb.y;
        const float q = 0.5f * (g00 * t0 * t0 + g11 * t1 * t1 + g22 * t2 * t2
                      + 2.f * (g01 * t0 * t1 + g02 * t0 * t2 + g12 * t1 * t2));
        const float w = __expf(-q);

        const int rk = atomicAdd(&cnt[l], 1);
        if (rk < CAPV) { dloc[l][rk] = (unsigned short)d; wloc[l][rk] = w; }
    };

    const uint4* bb4 = (const uint4*)(binbuf + (size_t)b * CAPBIN);
    const int n4 = n >> 2;
    for (int i = tid; i < n4; i += 256) {
        const uint4 p4 = bb4[i];
        process(p4.x); process(p4.y); process(p4.z); process(p4.w);
    }
    for (int i = (n4 << 2) + tid; i < n; i += 256)
        process(binbuf[(size_t)b * CAPBIN + i]);
    __syncthreads();

    // Phase 2: 4 waves x 8 vertices; per wave, 4 row-groups x 16B chunks.
    const int wid  = tid >> 6;
    const int lane = tid & 63;
    const int g    = lane >> 4;   // row group
    const int j    = lane & 15;   // 16B chunk (8 columns)
    const float4 bb0 = ((const float4*)bias)[2 * j];
    const float4 bb1 = ((const float4*)bias)[2 * j + 1];

    for (int l = wid * 8; l < wid * 8 + 8; ++l) {
        const int v = v0 + l;
        if (v >= N) break;
        const int deg = min(cnt[l], CAPV);

        float a0 = 0.f, a1 = 0.f, a2 = 0.f, a3 = 0.f;
        float a4 = 0.f, a5 = 0.f, a6 = 0.f, a7 = 0.f;
        float wsum = 0.f;

        for (int k = g; k < deg; k += 4) {
            const int   d = dloc[l][k];
            const float w = wloc[l][k];
            const uint4 u = ((const uint4*)(xwb + (size_t)d * FOUT))[j];
            a0 = fmaf(w, bfbits2f(u.x & 0xffffu), a0);
            a1 = fmaf(w, bfbits2f(u.x >> 16),     a1);
            a2 = fmaf(w, bfbits2f(u.y & 0xffffu), a2);
            a3 = fmaf(w, bfbits2f(u.y >> 16),     a3);
            a4 = fmaf(w, bfbits2f(u.z & 0xffffu), a4);
            a5 = fmaf(w, bfbits2f(u.z >> 16),     a5);
            a6 = fmaf(w, bfbits2f(u.w & 0xffffu), a6);
            a7 = fmaf(w, bfbits2f(u.w >> 16),     a7);
            wsum += w;
        }

        // fold 4 group partials (lane groups are 16 apart)
#pragma unroll
        for (int off = 16; off < 64; off <<= 1) {
            wsum += __shfl_xor(wsum, off, 64);
            a0 += __shfl_xor(a0, off, 64);
            a1 += __shfl_xor(a1, off, 64);
            a2 += __shfl_xor(a2, off, 64);
            a3 += __shfl_xor(a3, off, 64);
            a4 += __shfl_xor(a4, off, 64);
            a5 += __shfl_xor(a5, off, 64);
            a6 += __shfl_xor(a6, off, 64);
            a7 += __shfl_xor(a7, off, 64);
        }

        if (g == 0) {
            const float inv = 1.f / (wsum + EPSV);
            float4 o0, o1;
            o0.x = a0 * inv + bb0.x; o0.y = a1 * inv + bb0.y;
            o0.z = a2 * inv + bb0.z; o0.w = a3 * inv + bb0.w;
            o1.x = a4 * inv + bb1.x; o1.y = a5 * inv + bb1.y;
            o1.z = a6 * inv + bb1.z; o1.w = a7 * inv + bb1.w;
            float4* op = (float4*)(out + (size_t)v * FOUT + j * 8);
            op[0] = o0;
            op[1] = o1;
        }
    }
}

extern "C" void kernel_launch(void* const* d_in, const int* in_sizes, int n_in,
                              void* d_out, int out_size, void* d_ws, size_t ws_size,
                              hipStream_t stream) {
    const float* feat  = (const float*)d_in[0];
    const float* verts = (const float*)d_in[1];
    const int*   edges = (const int*)d_in[2];
    // d_in[3] = faces (unused)
    const float* W1    = (const float*)d_in[4];
    const float* b1    = (const float*)d_in[5];
    const float* W2    = (const float*)d_in[6];
    const float* b2    = (const float*)d_in[7];
    const float* Wc    = (const float*)d_in[8];
    const float* bias  = (const float*)d_in[9];

    const int N = in_sizes[0] / CIN;
    const int E = in_sizes[2] / 2;
    const int nbins = (N + BIGW - 1) >> BIG_SH;

    // workspace layout (256B-aligned chunks)
    char* p = (char*)d_ws;
    auto alloc = [&](size_t bytes) {
        char* r = p;
        p += (bytes + 255) & ~(size_t)255;
        return r;
    };
    short*          WcT    = (short*)alloc((size_t)CIN * FOUT * sizeof(short));
    short*          W1T    = (short*)alloc((size_t)HID * CIN * sizeof(short));
    unsigned short* xwb    = (unsigned short*)alloc((size_t)N * FOUT * sizeof(short));
    float*          Gp     = (float*)alloc((size_t)N * 8 * sizeof(float));
    float*          vertsP = (float*)alloc((size_t)N * 4 * sizeof(float));
    unsigned*       binbuf = (unsigned*)alloc((size_t)nbins * CAPBIN * sizeof(unsigned));
    int*            binctr = (int*)alloc((size_t)nbins * sizeof(int));
    float*          out    = (float*)d_out;

    const int prep_n = (N > CIN * FOUT) ? N : CIN * FOUT;
    prep_kernel<<<(prep_n + 255) / 256, 256, 0, stream>>>(Wc, W1, verts, WcT, W1T, vertsP,
                                                          binctr, N, nbins);

    bin_kernel<<<(E + 4095) / 4096, 256, 0, stream>>>(edges, binctr, binbuf, E, nbins);

    const int nwaves = (N + 15) / 16;
    vertex_mfma<<<(nwaves + 3) / 4, 256, 0, stream>>>(feat, WcT, W1T, b1, W2, b2, Gp, xwb, N);

    agg_kernel<<<nbins * NSUB, 256, 0, stream>>>(binctr, binbuf, vertsP, Gp, xwb, bias, out, N);
}

// Round 18
// 86.685 us; speedup vs baseline: 1.1885x; 1.1628x over previous
//
#include <hip/hip_runtime.h>
#include <hip/hip_bf16.h>

#define CIN  128
#define FOUT 128
#define HID  32
#define BIG_SH 7
#define BIGW  128           // 1 << BIG_SH
#define CAPBIN 2560         // coarse-bin capacity (mean 2048, +11 sigma)
#define SUBW  32            // agg sub-range width
#define NSUB  4             // BIGW / SUBW
#define CAPV  40            // per-vertex capacity (mean 16, Poisson +8 sigma)
#define EPSV 1e-8f

typedef __attribute__((ext_vector_type(8))) short bf16x8;
typedef __attribute__((ext_vector_type(4))) float f32x4;

__device__ inline short f2bf(float x) {
    union { float f; unsigned u; } v; v.f = x;
    unsigned r = v.u + 0x7fffu + ((v.u >> 16) & 1u);
    return (short)(r >> 16);
}
__device__ inline float bfbits2f(unsigned b) {
    union { unsigned u; float f; } v; v.u = b << 16;
    return v.f;
}

// ---------------------------------------------------------------------------
// Prep: WcT/W1T bf16 transposes, padded verts [N][4], zero bin counters.
// ---------------------------------------------------------------------------
__global__ void prep_kernel(const float* __restrict__ Wc,
                            const float* __restrict__ W1,
                            const float* __restrict__ verts,
                            short* __restrict__ WcT,
                            short* __restrict__ W1T,
                            float* __restrict__ vertsP,
                            int* __restrict__ binctr,
                            int N, int nbins) {
    const int idx = blockIdx.x * 256 + threadIdx.x;
    if (idx < CIN * FOUT) {
        const int c = idx >> 7, k = idx & 127;
        WcT[c * CIN + k] = f2bf(Wc[k * FOUT + c]);
    }
    if (idx < HID * CIN) {
        const int c = idx >> 7, k = idx & 127;
        W1T[c * CIN + k] = f2bf(W1[k * HID + c]);
    }
    if (idx < N) {
        vertsP[idx * 4 + 0] = verts[idx * 3 + 0];
        vertsP[idx * 4 + 1] = verts[idx * 3 + 1];
        vertsP[idx * 4 + 2] = verts[idx * 3 + 2];
        vertsP[idx * 4 + 3] = 0.f;
    }
    if (idx < nbins) binctr[idx] = 0;
}

// ---------------------------------------------------------------------------
// Fused bin || vertex kernel (block-specialized; the two bodies are data-
// independent). Blocks [0, nbb): two-level binning with block-owned run
// reservation (proven r13/r15). Blocks [nbb, nbb+nvb): per-16-vertex-wave
// MFMA pipeline. LDS is a union -> footprint = vertex path's 26.6 KB.
// ---------------------------------------------------------------------------
__global__ __launch_bounds__(256) void fused_kernel(
    const int* __restrict__ edges,
    int* __restrict__ binctr,
    unsigned* __restrict__ binbuf,
    const float* __restrict__ feat,
    const short* __restrict__ WcT,    // [FOUT][CIN] bf16
    const short* __restrict__ W1T,    // [HID][CIN] bf16
    const float* __restrict__ b1,
    const float* __restrict__ W2,     // [HID][9]
    const float* __restrict__ b2,
    float* __restrict__ Gp,           // [N][8] packed symmetric
    unsigned short* __restrict__ xwb, // [N][FOUT] bf16 bits
    int N, int E, int nbins, int nbb) {
    __shared__ union {
        struct {
            unsigned short xw[4][16][FOUT];
            float h[4][16][HID];
            float M[4][16][9];
        } v;
        struct {
            int cnt[512];
            int base[512];
        } b;
    } sm;

    const int bid = blockIdx.x;
    const int tid = threadIdx.x;

    if (bid < nbb) {
        // ------------------------- bin body -------------------------
        for (int b = tid; b < nbins; b += 256) sm.b.cnt[b] = 0;
        __syncthreads();

        int ebin[16], erank[16]; unsigned epack[16];
        const int e0 = bid * 4096;
#pragma unroll
        for (int i = 0; i < 16; ++i) {
            const int e = e0 + i * 256 + tid;
            ebin[i] = -1;
            if (e < E) {
                const int s = edges[e];
                const int d = edges[E + e];
                ebin[i] = s >> BIG_SH;
                epack[i] = ((unsigned)(s & (BIGW - 1)) << 16) | (unsigned)d;
                erank[i] = atomicAdd(&sm.b.cnt[ebin[i]], 1);
            }
        }
        __syncthreads();
        for (int b = tid; b < nbins; b += 256) {
            const int c = sm.b.cnt[b];
            sm.b.base[b] = c ? atomicAdd(&binctr[b], c) : 0;
        }
        __syncthreads();
#pragma unroll
        for (int i = 0; i < 16; ++i) {
            if (ebin[i] >= 0) {
                const int rk = sm.b.base[ebin[i]] + erank[i];
                if (rk < CAPBIN) binbuf[(size_t)ebin[i] * CAPBIN + rk] = epack[i];
            }
        }
        return;
    }

    // ------------------------- vertex body -------------------------
    const int lv = bid - nbb;
    if (lv * 64 >= N) return;

    const int wid  = tid >> 6;
    const int lane = tid & 63;
    const int v0   = (lv * 4 + wid) * 16;
    const int r    = lane & 15;
    const int hi   = lane >> 4;
    const int vr   = min(v0 + r, N - 1);

    bf16x8 a[4];
#pragma unroll
    for (int kt = 0; kt < 4; ++kt) {
        const float* src = feat + (size_t)vr * CIN + kt * 32 + hi * 8;
        const float4 f0 = ((const float4*)src)[0];
        const float4 f1 = ((const float4*)src)[1];
        bf16x8 t;
        t[0] = f2bf(f0.x); t[1] = f2bf(f0.y); t[2] = f2bf(f0.z); t[3] = f2bf(f0.w);
        t[4] = f2bf(f1.x); t[5] = f2bf(f1.y); t[6] = f2bf(f1.z); t[7] = f2bf(f1.w);
        a[kt] = t;
    }

#pragma unroll
    for (int ct = 0; ct < 8; ++ct) {
        f32x4 acc = {0.f, 0.f, 0.f, 0.f};
#pragma unroll
        for (int kt = 0; kt < 4; ++kt) {
            const bf16x8 b = *((const bf16x8*)(WcT + (size_t)(ct * 16 + r) * CIN + kt * 32 + hi * 8));
            acc = __builtin_amdgcn_mfma_f32_16x16x32_bf16(a[kt], b, acc, 0, 0, 0);
        }
#pragma unroll
        for (int reg = 0; reg < 4; ++reg)
            sm.v.xw[wid][hi * 4 + reg][ct * 16 + r] = (unsigned short)f2bf(acc[reg]);
    }

#pragma unroll
    for (int row = 0; row < 16; ++row) {
        if (v0 + row < N) {
            const unsigned d = ((const unsigned*)sm.v.xw[wid][row])[lane];
            ((unsigned*)(xwb + (size_t)(v0 + row) * FOUT))[lane] = d;
        }
    }

#pragma unroll
    for (int ct = 0; ct < 2; ++ct) {
        f32x4 acc = {0.f, 0.f, 0.f, 0.f};
#pragma unroll
        for (int kt = 0; kt < 4; ++kt) {
            const bf16x8 b = *((const bf16x8*)(W1T + (size_t)(ct * 16 + r) * CIN + kt * 32 + hi * 8));
            acc = __builtin_amdgcn_mfma_f32_16x16x32_bf16(a[kt], b, acc, 0, 0, 0);
        }
        const float bb = b1[ct * 16 + r];
#pragma unroll
        for (int reg = 0; reg < 4; ++reg)
            sm.v.h[wid][hi * 4 + reg][ct * 16 + r] = fmaxf(acc[reg] + bb, 0.f);
    }
    __syncthreads();

    for (int idx = lane; idx < 144; idx += 64) {
        const int v = idx / 9, t = idx - v * 9;
        float m = b2[t];
#pragma unroll
        for (int k = 0; k < HID; ++k)
            m = fmaf(sm.v.h[wid][v][k], W2[k * 9 + t], m);
        sm.v.M[wid][v][t] = m;
    }
    __syncthreads();

    for (int idx = lane; idx < 96; idx += 64) {
        const int v = idx / 6, t = idx - v * 6;
        const int i = (t >= 3) + (t >= 5);
        const int j = t - (t >= 3) * 2 - (t >= 5);
        float g = 0.f;
#pragma unroll
        for (int k = 0; k < 3; ++k)
            g += sm.v.M[wid][v][k * 3 + i] * sm.v.M[wid][v][k * 3 + j];
        if (v0 + v < N) Gp[(size_t)(v0 + v) * 8 + t] = g;
    }
}

// ---------------------------------------------------------------------------
// Aggregation (r15 variant — best measured): 4 sub-blocks per coarse bin.
// Single scan: filter own sub-range, compute w (s-side LDS preload), direct
// LDS bucket by vertex. Then 4 waves x 8 vertices do 8-wide unrolled
// wave-wide xwb row gathers from LDS-broadcast (d,w).
// ---------------------------------------------------------------------------
__global__ __launch_bounds__(256) void agg_kernel(const int* __restrict__ binctr,
                                                  const unsigned* __restrict__ binbuf,
                                                  const float* __restrict__ vertsP,
                                                  const float* __restrict__ Gp,
                                                  const unsigned short* __restrict__ xwb,
                                                  const float* __restrict__ bias,
                                                  float* __restrict__ out,
                                                  int N) {
    __shared__ unsigned short dloc[SUBW][CAPV];
    __shared__ float wloc[SUBW][CAPV];
    __shared__ int cnt[SUBW];
    __shared__ float sG[SUBW * 8];
    __shared__ float sV[SUBW * 4];

    const int b   = blockIdx.x >> 2;
    const int sub = blockIdx.x & 3;
    const int v0  = (b << BIG_SH) + sub * SUBW;
    const int tid = threadIdx.x;

    if (tid < SUBW) cnt[tid] = 0;
    {
        const int v = v0 + (tid >> 3);
        sG[tid] = (v < N) ? Gp[(size_t)v * 8 + (tid & 7)] : 0.f;
    }
    if (tid < SUBW * 4) {
        const int v2 = v0 + (tid >> 2);
        sV[tid] = (v2 < N) ? vertsP[(size_t)v2 * 4 + (tid & 3)] : 0.f;
    }
    __syncthreads();

    const int n = min(binctr[b], CAPBIN);

    for (int i = tid; i < n; i += 256) {
        const unsigned p = binbuf[(size_t)b * CAPBIN + i];
        const int ls = (int)(p >> 16);
        if ((ls >> 5) != sub) continue;
        const int l = ls & 31;
        const int d = (int)(p & 0xffffu);

        const float4 vd = ((const float4*)vertsP)[d];
        const float4 ha = ((const float4*)(Gp + (size_t)d * 8))[0];
        const float2 hb = ((const float2*)(Gp + (size_t)d * 8 + 4))[0];
        const float* gs = &sG[l * 8];
        const float* vv = &sV[l * 4];
        const float t0 = vd.x - vv[0], t1 = vd.y - vv[1], t2 = vd.z - vv[2];
        const float g00 = gs[0] + ha.x, g01 = gs[1] + ha.y, g02 = gs[2] + ha.z;
        const float g11 = gs[3] + ha.w, g12 = gs[4] + hb.x, g22 = gs[5] + hb.y;
        const float q = 0.5f * (g00 * t0 * t0 + g11 * t1 * t1 + g22 * t2 * t2
                      + 2.f * (g01 * t0 * t1 + g02 * t0 * t2 + g12 * t1 * t2));
        const float w = __expf(-q);

        const int rk = atomicAdd(&cnt[l], 1);
        if (rk < CAPV) { dloc[l][rk] = (unsigned short)d; wloc[l][rk] = w; }
    }
    __syncthreads();

    const int wid  = tid >> 6;
    const int lane = tid & 63;
    const float2 bb = ((const float2*)bias)[lane];

    for (int l = wid * 8; l < wid * 8 + 8; ++l) {
        const int v = v0 + l;
        if (v >= N) break;
        const int deg = min(cnt[l], CAPV);

        float ax = 0.f, ay = 0.f, wsum = 0.f;
        int k = 0;
        for (; k + 8 <= deg; k += 8) {
            int   d_[8]; float w_[8]; unsigned u_[8];
#pragma unroll
            for (int j = 0; j < 8; ++j) { d_[j] = dloc[l][k + j]; w_[j] = wloc[l][k + j]; }
#pragma unroll
            for (int j = 0; j < 8; ++j) u_[j] = ((const unsigned*)(xwb + (size_t)d_[j] * FOUT))[lane];
#pragma unroll
            for (int j = 0; j < 8; ++j) {
                ax = fmaf(w_[j], bfbits2f(u_[j] & 0xffffu), ax);
                ay = fmaf(w_[j], bfbits2f(u_[j] >> 16), ay);
                wsum += w_[j];
            }
        }
        for (; k < deg; ++k) {
            const int   d0 = dloc[l][k];
            const float w0 = wloc[l][k];
            const unsigned u0 = ((const unsigned*)(xwb + (size_t)d0 * FOUT))[lane];
            ax = fmaf(w0, bfbits2f(u0 & 0xffffu), ax);
            ay = fmaf(w0, bfbits2f(u0 >> 16), ay);
            wsum += w0;
        }

        const float inv = 1.f / (wsum + EPSV);
        float2 o;
        o.x = ax * inv + bb.x;
        o.y = ay * inv + bb.y;
        ((float2*)(out + (size_t)v * FOUT))[lane] = o;
    }
}

extern "C" void kernel_launch(void* const* d_in, const int* in_sizes, int n_in,
                              void* d_out, int out_size, void* d_ws, size_t ws_size,
                              hipStream_t stream) {
    const float* feat  = (const float*)d_in[0];
    const float* verts = (const float*)d_in[1];
    const int*   edges = (const int*)d_in[2];
    // d_in[3] = faces (unused)
    const float* W1    = (const float*)d_in[4];
    const float* b1    = (const float*)d_in[5];
    const float* W2    = (const float*)d_in[6];
    const float* b2    = (const float*)d_in[7];
    const float* Wc    = (const float*)d_in[8];
    const float* bias  = (const float*)d_in[9];

    const int N = in_sizes[0] / CIN;
    const int E = in_sizes[2] / 2;
    const int nbins = (N + BIGW - 1) >> BIG_SH;

    // workspace layout (256B-aligned chunks)
    char* p = (char*)d_ws;
    auto alloc = [&](size_t bytes) {
        char* r = p;
        p += (bytes + 255) & ~(size_t)255;
        return r;
    };
    short*          WcT    = (short*)alloc((size_t)CIN * FOUT * sizeof(short));
    short*          W1T    = (short*)alloc((size_t)HID * CIN * sizeof(short));
    unsigned short* xwb    = (unsigned short*)alloc((size_t)N * FOUT * sizeof(short));
    float*          Gp     = (float*)alloc((size_t)N * 8 * sizeof(float));
    float*          vertsP = (float*)alloc((size_t)N * 4 * sizeof(float));
    unsigned*       binbuf = (unsigned*)alloc((size_t)nbins * CAPBIN * sizeof(unsigned));
    int*            binctr = (int*)alloc((size_t)nbins * sizeof(int));
    float*          out    = (float*)d_out;

    const int prep_n = (N > CIN * FOUT) ? N : CIN * FOUT;
    prep_kernel<<<(prep_n + 255) / 256, 256, 0, stream>>>(Wc, W1, verts, WcT, W1T, vertsP,
                                                          binctr, N, nbins);

    const int nbb = (E + 4095) / 4096;
    const int nvb = ((N + 15) / 16 + 3) / 4;
    fused_kernel<<<nbb + nvb, 256, 0, stream>>>(edges, binctr, binbuf,
                                                feat, WcT, W1T, b1, W2, b2, Gp, xwb,
                                                N, E, nbins, nbb);

    agg_kernel<<<nbins * NSUB, 256, 0, stream>>>(binctr, binbuf, vertsP, Gp, xwb, bias, out, N);
}